// Round 8
// baseline (726.836 us; speedup 1.0000x reference)
//
#include <hip/hip_runtime.h>

#define N_ROWS   131072
#define D_IN     512
#define D_H      128
#define K_CODES  256
#define PNT      256

// workspace layout (bytes); REQUIRES ws_size >= ~70 MB
#define WS_USED   64           // 768 ints
#define WS_NORMS  3200         // 768 f32
#define WS_WSB    8192         // 448 KB bf16 fragments
#define WS_IDX    466944       // 3 x 131072 ints (winning codes per stage)
#define WS_LAT    2097152      // 131072 x 128 f32 latent/rem, updated in place (64 MB)

typedef __attribute__((ext_vector_type(8))) short bf16x8;
typedef __attribute__((ext_vector_type(4))) float f32x4;

__device__ inline unsigned short f2bf(float f) {
    unsigned u = __float_as_uint(f);
    return (unsigned short)((u + 0x7FFFu + ((u >> 16) & 1u)) >> 16);
}
__device__ inline ushort4 f2bf4(float4 v) {
    return make_ushort4(f2bf(v.x), f2bf(v.y), f2bf(v.z), f2bf(v.w));
}
__device__ inline bf16x8 f2bf8(float4 a, float4 b) {
    bf16x8 r;
    r[0] = (short)f2bf(a.x); r[1] = (short)f2bf(a.y); r[2] = (short)f2bf(a.z); r[3] = (short)f2bf(a.w);
    r[4] = (short)f2bf(b.x); r[5] = (short)f2bf(b.y); r[6] = (short)f2bf(b.z); r[7] = (short)f2bf(b.w);
    return r;
}
__device__ inline float4 add4(float4 a, float4 b) {
    return make_float4(a.x + b.x, a.y + b.y, a.z + b.z, a.w + b.w);
}

// ---------------- prep: reorder weights/codebooks into MFMA B-fragment order ----------------
// frag(ct,ks): lane = qd*16+nn holds B[n=ct*16+nn][k=ks*32+qd*8+j], j=0..7.
// wsb (ushorts): [0..65535] Wenc (kc=0..3) | [65536..163839] cb (t,half) | [163840..229375] Wdec (c=0..3)
__global__ void rqvae_prep(const float* __restrict__ Wenc,
                           const float* __restrict__ Wdec,
                           const float* __restrict__ cb0,
                           const float* __restrict__ cb1,
                           const float* __restrict__ cb2,
                           unsigned short* __restrict__ wsb,
                           float* __restrict__ norms)
{
    const int tid = threadIdx.x;
    const int b = blockIdx.x;
    const float* cbs[3] = {cb0, cb1, cb2};
    if (b < 112) {
        const int g = b * 256 + tid;            // ushort8 group id, 0..28671
        const int lane = g & 63, ks = (g >> 6) & 3, ct = (g >> 8) & 7;
        const int nn = lane & 15, qd = lane >> 4;
        const float* src;
        if (g < 8192) {                         // Wenc: kc = g>>11
            const int kc = g >> 11;
            src = Wenc + (ct * 16 + nn) * D_IN + kc * 128 + ks * 32 + qd * 8;
        } else if (g < 20480) {                 // cb: t = (g-8192)>>12, half = bit 11
            const int r = g - 8192;
            const int t = r >> 12, half = (r >> 11) & 1;
            src = cbs[t] + (long)(half * 128 + ct * 16 + nn) * D_H + ks * 32 + qd * 8;
        } else {                                // Wdec: c = (g-20480)>>11
            const int r = g - 20480;
            const int c = r >> 11;
            src = Wdec + (long)(c * 128 + ct * 16 + nn) * D_H + ks * 32 + qd * 8;
        }
        float4 v0 = *(const float4*)(src);
        float4 v1 = *(const float4*)(src + 4);
        *(ushort4*)(wsb + (long)g * 8)     = f2bf4(v0);
        *(ushort4*)(wsb + (long)g * 8 + 4) = f2bf4(v1);
    } else {
        const int t = b - 112;                  // norm blocks: one code per thread
        const float4* r = (const float4*)(cbs[t] + (long)tid * D_H);
        float s = 0.f;
        #pragma unroll
        for (int d = 0; d < 32; ++d) { float4 v = r[d]; s += v.x*v.x + v.y*v.y + v.z*v.z + v.w*v.w; }
        norms[t * K_CODES + tid] = -0.5f * s;
    }
}

// ---------------- K2: latent = emb @ Wenc^T, fp32 out ----------------
// Whole Wenc (128 KB frags) resident in LDS; one barrier total. 256 blocks x 1024
// threads = exactly 1 block/CU, 16 waves, each streaming 32 rows independently.
__global__ __launch_bounds__(1024, 4) void rqvae_latent(
    const float* __restrict__ emb,
    const unsigned short* __restrict__ wsb,
    float* __restrict__ lat)
{
    __shared__ unsigned short sW[65536];       // 128 KB
    const int tid = threadIdx.x;
    const int wv = tid >> 6, lane = tid & 63, nn = lane & 15, qd = lane >> 4;
    {
        const bf16x8* src = (const bf16x8*)wsb;
        bf16x8* dst = (bf16x8*)sW;
        #pragma unroll
        for (int i = 0; i < 8; ++i) dst[tid + i * 1024] = src[tid + i * 1024];
    }
    __syncthreads();
    const long base = (long)blockIdx.x * 512;
    #pragma unroll 1
    for (int tt = 0; tt < 2; ++tt) {
        const long row0 = base + wv * 32 + tt * 16;
        f32x4 acc[8];
        #pragma unroll
        for (int ct = 0; ct < 8; ++ct) acc[ct] = {0.f,0.f,0.f,0.f};
        #pragma unroll 1
        for (int kc = 0; kc < 4; ++kc) {
            const float* ar = emb + (row0 + nn) * D_IN + kc * 128 + qd * 8;
            bf16x8 af[4];
            #pragma unroll
            for (int ks = 0; ks < 4; ++ks)
                af[ks] = f2bf8(*(const float4*)(ar + ks * 32), *(const float4*)(ar + ks * 32 + 4));
            #pragma unroll
            for (int ct = 0; ct < 8; ++ct)
                #pragma unroll
                for (int ks = 0; ks < 4; ++ks) {
                    bf16x8 bf = *(const bf16x8*)&sW[kc * 16384 + (ct * 4 + ks) * 512 + lane * 8];
                    acc[ct] = __builtin_amdgcn_mfma_f32_16x16x32_bf16(af[ks], bf, acc[ct], 0, 0, 0);
                }
        }
        #pragma unroll
        for (int ct = 0; ct < 8; ++ct)
            #pragma unroll
            for (int e = 0; e < 4; ++e)
                lat[(row0 + qd * 4 + e) * D_H + ct * 16 + nn] = acc[ct][e];
    }
}

// ---------------- K3/K4/K5: one RQ stage ----------------
// Whole cb_t frags (64 KB) + norms in LDS; one barrier. 512 blocks x 512 threads,
// 2 blocks/CU. rem fp32 updated in place (bit-identical chain to the monolith:
// distance A = f2bf(rem) on the fly; rr from fp32 rem minus fp32 gathered cb).
__global__ __launch_bounds__(512, 4) void rqvae_stage(
    float* __restrict__ rem,
    const float* __restrict__ cb,
    const unsigned short* __restrict__ wsb,
    const float* __restrict__ norms,
    const int t, const int last,
    int* __restrict__ used,
    int* __restrict__ idxo,
    float* __restrict__ acc_rq)
{
    __shared__ unsigned short sC[32768];       // 64 KB
    __shared__ float s_cn[K_CODES];
    const int tid = threadIdx.x;
    const int wv = tid >> 6, lane = tid & 63, nn = lane & 15, qd = lane >> 4;
    {
        const bf16x8* src = (const bf16x8*)(wsb + 65536 + t * 32768);
        bf16x8* dst = (bf16x8*)sC;
        #pragma unroll
        for (int i = 0; i < 8; ++i) dst[tid + i * 512] = src[tid + i * 512];
    }
    if (tid < K_CODES) s_cn[tid] = norms[t * K_CODES + tid];
    __syncthreads();
    const long base = (long)blockIdx.x * 256;
    float local_rq = 0.f;
    #pragma unroll 1
    for (int tt = 0; tt < 2; ++tt) {
        const long row0 = base + wv * 32 + tt * 16;
        bf16x8 af[4];
        {
            const float* rr_ = rem + (row0 + nn) * D_H + qd * 8;
            #pragma unroll
            for (int ks = 0; ks < 4; ++ks)
                af[ks] = f2bf8(*(const float4*)(rr_ + ks * 32), *(const float4*)(rr_ + ks * 32 + 4));
        }
        float bv[4]; int bi[4];
        #pragma unroll
        for (int e = 0; e < 4; ++e) { bv[e] = -3.402823466e38f; bi[e] = 0; }
        #pragma unroll 2
        for (int ctc = 0; ctc < 16; ++ctc) {
            f32x4 s = {0.f,0.f,0.f,0.f};
            #pragma unroll
            for (int ks = 0; ks < 4; ++ks) {
                bf16x8 bf = *(const bf16x8*)&sC[(ctc * 4 + ks) * 512 + lane * 8];
                s = __builtin_amdgcn_mfma_f32_16x16x32_bf16(af[ks], bf, s, 0, 0, 0);
            }
            const int code = ctc * 16 + nn;
            const float cn = s_cn[code];
            #pragma unroll
            for (int e = 0; e < 4; ++e) {
                const float v = s[e] + cn;
                if (v > bv[e] || (v == bv[e] && code < bi[e])) { bv[e] = v; bi[e] = code; }
            }
        }
        // argmax over the 16 nn-lanes of each quad (tie -> lowest index)
        #pragma unroll
        for (int e = 0; e < 4; ++e) {
            float v = bv[e]; int i0 = bi[e];
            #pragma unroll
            for (int m = 8; m >= 1; m >>= 1) {
                const float ov = __shfl_xor(v, m);
                const int   oi = __shfl_xor(i0, m);
                if (ov > v || (ov == v && oi < i0)) { v = ov; i0 = oi; }
            }
            bi[e] = i0;
            if (nn == 0) { used[t * K_CODES + i0] = 1; idxo[row0 + qd * 4 + e] = i0; }
        }
        // rem update (fp32, in place) + rq accumulation
        #pragma unroll
        for (int ct = 0; ct < 8; ++ct)
            #pragma unroll
            for (int e = 0; e < 4; ++e) {
                const long ro = (row0 + qd * 4 + e) * D_H + ct * 16 + nn;
                const float rv = rem[ro];
                const float c  = cb[(long)bi[e] * D_H + ct * 16 + nn];
                const float rr = rv - c;
                local_rq += rr * rr;
                if (!last) rem[ro] = rr;
            }
    }
    #pragma unroll
    for (int m = 32; m >= 1; m >>= 1) local_rq += __shfl_xor(local_rq, m);
    if (lane == 0) atomicAdd(acc_rq, local_rq);
}

// ---------------- K6: recon = restored @ Wdec^T, diff vs fp32 emb ----------------
// Whole Wdec frags (128 KB) in LDS; restored re-gathered fp32 as (c0+c1)+c2
// (identical to the monolith's res accumulation order), f2bf to A-frags.
__global__ __launch_bounds__(1024, 4) void rqvae_recon(
    const float* __restrict__ emb,
    const float* __restrict__ cb0,
    const float* __restrict__ cb1,
    const float* __restrict__ cb2,
    const unsigned short* __restrict__ wsb,
    const int* __restrict__ idx,
    float* __restrict__ acc_recon)
{
    __shared__ unsigned short sW[65536];       // 128 KB
    const int tid = threadIdx.x;
    const int wv = tid >> 6, lane = tid & 63, nn = lane & 15, qd = lane >> 4;
    {
        const bf16x8* src = (const bf16x8*)(wsb + 163840);
        bf16x8* dst = (bf16x8*)sW;
        #pragma unroll
        for (int i = 0; i < 8; ++i) dst[tid + i * 1024] = src[tid + i * 1024];
    }
    __syncthreads();
    const long base = (long)blockIdx.x * 512;
    float local_rec = 0.f;
    #pragma unroll 1
    for (int tt = 0; tt < 2; ++tt) {
        const long row0 = base + wv * 32 + tt * 16;
        const int i0 = idx[row0 + nn];
        const int i1 = idx[N_ROWS + row0 + nn];
        const int i2 = idx[2 * N_ROWS + row0 + nn];
        bf16x8 af[4];
        #pragma unroll
        for (int ks = 0; ks < 4; ++ks) {
            const int ko = ks * 32 + qd * 8;
            float4 a0 = *(const float4*)(cb0 + (long)i0 * D_H + ko);
            float4 b0 = *(const float4*)(cb0 + (long)i0 * D_H + ko + 4);
            float4 a1 = *(const float4*)(cb1 + (long)i1 * D_H + ko);
            float4 b1 = *(const float4*)(cb1 + (long)i1 * D_H + ko + 4);
            float4 a2 = *(const float4*)(cb2 + (long)i2 * D_H + ko);
            float4 b2 = *(const float4*)(cb2 + (long)i2 * D_H + ko + 4);
            af[ks] = f2bf8(add4(add4(a0, a1), a2), add4(add4(b0, b1), b2));
        }
        #pragma unroll 4
        for (int ctc = 0; ctc < 32; ++ctc) {
            f32x4 r = {0.f,0.f,0.f,0.f};
            #pragma unroll
            for (int ks = 0; ks < 4; ++ks) {
                bf16x8 bf = *(const bf16x8*)&sW[(ctc * 4 + ks) * 512 + lane * 8];
                r = __builtin_amdgcn_mfma_f32_16x16x32_bf16(af[ks], bf, r, 0, 0, 0);
            }
            const int col = ctc * 16 + nn;
            #pragma unroll
            for (int e = 0; e < 4; ++e) {
                const float d = r[e] - emb[(row0 + qd * 4 + e) * D_IN + col];
                local_rec += d * d;
            }
        }
    }
    #pragma unroll
    for (int m = 32; m >= 1; m >>= 1) local_rec += __shfl_xor(local_rec, m);
    if (lane == 0) atomicAdd(acc_recon, local_rec);
}

__global__ void rqvae_finalize(const float* __restrict__ acc,
                               const int* __restrict__ used,
                               float* __restrict__ out)
{
    __shared__ int s_sum[4];
    const int tid = threadIdx.x;
    for (int t = 0; t < 3; ++t) {
        int v = (used[t * K_CODES + tid] != 0) ? 1 : 0;
        #pragma unroll
        for (int off = 32; off >= 1; off >>= 1) v += __shfl_down(v, off);
        if ((tid & 63) == 0) s_sum[tid >> 6] = v;
        __syncthreads();
        if (tid == 0) out[3 + t] = (float)(s_sum[0] + s_sum[1] + s_sum[2] + s_sum[3]);
        __syncthreads();
    }
    if (tid == 0) {
        const float rq    = 1.25f * acc[0] / ((float)N_ROWS * 128.0f);
        const float recon =         acc[1] / ((float)N_ROWS * 512.0f);
        out[0] = recon + rq;
        out[1] = recon;
        out[2] = rq;
    }
}

extern "C" void kernel_launch(void* const* d_in, const int* in_sizes, int n_in,
                              void* d_out, int out_size, void* d_ws, size_t ws_size,
                              hipStream_t stream) {
    const float* emb  = (const float*)d_in[0];
    const float* Wenc = (const float*)d_in[1];
    const float* Wdec = (const float*)d_in[2];
    const float* cb0  = (const float*)d_in[3];
    const float* cb1  = (const float*)d_in[4];
    const float* cb2  = (const float*)d_in[5];

    float* ws_f  = (float*)d_ws;
    int*   used  = (int*)((char*)d_ws + WS_USED);
    float* norms = (float*)((char*)d_ws + WS_NORMS);
    unsigned short* wsb = (unsigned short*)((char*)d_ws + WS_WSB);
    int*   idx   = (int*)((char*)d_ws + WS_IDX);
    float* lat   = (float*)((char*)d_ws + WS_LAT);

    hipMemsetAsync(d_ws, 0, 3200, stream);
    rqvae_prep<<<115, PNT, 0, stream>>>(Wenc, Wdec, cb0, cb1, cb2, wsb, norms);
    rqvae_latent<<<256, 1024, 0, stream>>>(emb, wsb, lat);
    rqvae_stage<<<512, 512, 0, stream>>>(lat, cb0, wsb, norms, 0, 0, used, idx,             ws_f + 0);
    rqvae_stage<<<512, 512, 0, stream>>>(lat, cb1, wsb, norms, 1, 0, used, idx + N_ROWS,    ws_f + 0);
    rqvae_stage<<<512, 512, 0, stream>>>(lat, cb2, wsb, norms, 2, 1, used, idx + 2*N_ROWS,  ws_f + 0);
    rqvae_recon<<<256, 1024, 0, stream>>>(emb, cb0, cb1, cb2, wsb, idx, ws_f + 1);
    rqvae_finalize<<<1, PNT, 0, stream>>>(ws_f, used, (float*)d_out);
}

// Round 9
// 564.910 us; speedup vs baseline: 1.2866x; 1.2866x over previous
//
#include <hip/hip_runtime.h>

#define N_ROWS   131072
#define D_IN     512
#define D_H      128
#define K_CODES  256
#define NT       256          // 4 waves
#define RPB      128          // rows per block: 32 per wave (2 x 16-row MFMA tiles)
#define NBLK     (N_ROWS / RPB)
#define SA       136          // s_A row stride in bf16 elems (272 B, breaks power-of-2)

typedef __attribute__((ext_vector_type(8))) short bf16x8;
typedef __attribute__((ext_vector_type(4))) float f32x4;

__device__ inline unsigned short f2bf(float f) {
    unsigned u = __float_as_uint(f);
    return (unsigned short)((u + 0x7FFFu + ((u >> 16) & 1u)) >> 16);
}
__device__ inline ushort4 f2bf4(float4 v) {
    return make_ushort4(f2bf(v.x), f2bf(v.y), f2bf(v.z), f2bf(v.w));
}
// packed RNE f32->bf16 pair: D = {bf16(lo), bf16(hi)} — bit-identical to f2bf (RNE)
__device__ __forceinline__ unsigned cvtpk(float lo, float hi) {
    unsigned r;
    asm("v_cvt_pk_bf16_f32 %0, %1, %2" : "=v"(r) : "v"(lo), "v"(hi));
    return r;
}

// async global->LDS DMA, 16B per lane; LDS dest is wave-uniform base + lane*16
typedef const __attribute__((address_space(1))) void* gv_t;
typedef __attribute__((address_space(3))) void* lv_t;
__device__ __forceinline__ void gll16(const unsigned short* g, unsigned short* l) {
    __builtin_amdgcn_global_load_lds((gv_t)g, (lv_t)l, 16, 0, 0);
}

// ---------------- prep: reorder weights/codebooks into MFMA B-fragment order ----------------
// B-fragment order: frag(ct,ks) is 64 lanes x 8 bf16, lane = qd*16+nn holds
// B[n = ct*16+nn][k = ks*32 + qd*8 + j], j=0..7.  One 32KB "round" = 8 ct x 4 ks.
// wsb layout (ushorts): [0..65535] Wenc rounds kc=0..3 | [65536..163839] cb (t,half) rounds | [163840..229375] Wdec rounds c=0..3
__global__ void rqvae_prep(const float* __restrict__ Wenc,
                           const float* __restrict__ Wdec,
                           const float* __restrict__ cb0,
                           const float* __restrict__ cb1,
                           const float* __restrict__ cb2,
                           unsigned short* __restrict__ wsb,
                           float* __restrict__ norms)
{
    const int tid = threadIdx.x;
    const int b = blockIdx.x;
    const float* cbs[3] = {cb0, cb1, cb2};
    if (b < 112) {
        const int g = b * 256 + tid;            // ushort8 group id, 0..28671
        const int lane = g & 63, ks = (g >> 6) & 3, ct = (g >> 8) & 7;
        const int nn = lane & 15, qd = lane >> 4;
        const float* src;
        if (g < 8192) {                         // Wenc: kc = g>>11
            const int kc = g >> 11;
            src = Wenc + (ct * 16 + nn) * D_IN + kc * 128 + ks * 32 + qd * 8;
        } else if (g < 20480) {                 // cb: t = (g-8192)>>12, half = bit 11
            const int r = g - 8192;
            const int t = r >> 12, half = (r >> 11) & 1;
            src = cbs[t] + (long)(half * 128 + ct * 16 + nn) * D_H + ks * 32 + qd * 8;
        } else {                                // Wdec: c = (g-20480)>>11
            const int r = g - 20480;
            const int c = r >> 11;
            src = Wdec + (long)(c * 128 + ct * 16 + nn) * D_H + ks * 32 + qd * 8;
        }
        float4 v0 = *(const float4*)(src);
        float4 v1 = *(const float4*)(src + 4);
        *(ushort4*)(wsb + (long)g * 8)     = f2bf4(v0);
        *(ushort4*)(wsb + (long)g * 8 + 4) = f2bf4(v1);
    } else {
        const int t = b - 112;                  // norm blocks: one code per thread
        const float4* r = (const float4*)(cbs[t] + (long)tid * D_H);
        float s = 0.f;
        #pragma unroll
        for (int d = 0; d < 32; ++d) { float4 v = r[d]; s += v.x*v.x + v.y*v.y + v.z*v.z + v.w*v.w; }
        norms[t * K_CODES + tid] = -0.5f * s;
    }
}

// ---------------- main ----------------
// Round-7 champion structure (best measured: 280us main / 544 total) + TWO
// surgical pipe-work cuts, sync structure untouched:
//  (1) B staging via global_load_lds width-16 DMA (was 8 global_load_dwordx4 +
//      8 ds_write_b128 per thread per round): removes ~20% of LDS-unit load and
//      the copy's VGPR round trip. Copy is linear -> DMA-compatible
//      (dest byte = wave-uniform (wv*64+i*256)*16 + lane*16).
//  (2) A-staging f32->bf16 via v_cvt_pk_bf16_f32 (1 op / 2 elems, RNE ==
//      manual f2bf bit-hack): cuts ~800 VALU ops/thread from phase 1.
// Fill-kernel context: harness re-poisons the 1GB workspace at ~160us/iter
// (measured round 8); that is a fixed floor outside kernel control.
__global__ __launch_bounds__(NT, 2) void rqvae_main(
    const float* __restrict__ emb,
    const float* __restrict__ cb0,
    const float* __restrict__ cb1,
    const float* __restrict__ cb2,
    const unsigned short* __restrict__ wsb,
    const float* __restrict__ norms,
    float* __restrict__ acc_rq,
    float* __restrict__ acc_recon,
    int* __restrict__ used)
{
    __shared__ unsigned short s_A[RPB * SA];   // 34816 B: A operand (emb chunk / rem / restored), padded
    __shared__ unsigned short s_B[16384];      // 32768 B: one B round, fragment-linear
    __shared__ float s_cn[3 * K_CODES];        // 3072 B

    const int tid  = threadIdx.x;
    const int wv   = tid >> 6;
    const int lane = tid & 63;
    const int nn   = lane & 15;
    const int qd   = lane >> 4;
    const long blkRow = (long)blockIdx.x * RPB;
    const int rot  = (blockIdx.x >> 3) & 3;    // same-XCD decorrelator (neutral but harmless)
    const float* cbs[3] = {cb0, cb1, cb2};

    for (int i = tid; i < 3 * K_CODES; i += NT) s_cn[i] = norms[i];

    // B: 32KB round staged by DMA, linear layout (16B per thread x 8)
#define STAGEB(roundbase) do {                                                  \
        const unsigned short* _s = (roundbase);                                 \
        _Pragma("unroll")                                                       \
        for (int _i = 0; _i < 8; ++_i)                                          \
            gll16(_s + (tid + _i * NT) * 8, s_B + (tid + _i * NT) * 8);         \
    } while (0)

    f32x4 rem[2][8], res[2][8];
    #pragma unroll
    for (int rt = 0; rt < 2; ++rt)
        #pragma unroll
        for (int ct = 0; ct < 8; ++ct) { rem[rt][ct] = {0.f,0.f,0.f,0.f}; res[rt][ct] = {0.f,0.f,0.f,0.f}; }

    // ---- Phase 1: latent = emb @ Wenc^T (4 rounds of K=128, rotated order) ----
    for (int kk = 0; kk < 4; ++kk) {
        const int kc = (kk + rot) & 3;
        __syncthreads();
        STAGEB(wsb + kc * 16384);
        #pragma unroll
        for (int it = 0; it < 16; ++it) {                   // A: 128 rows x 32 float4
            const int g = tid + it * NT, row = g >> 5, c4 = g & 31;
            float4 v = *(const float4*)(emb + (blkRow + row) * D_IN + kc * 128 + c4 * 4);
            uint2 p; p.x = cvtpk(v.x, v.y); p.y = cvtpk(v.z, v.w);
            *(uint2*)&s_A[row * SA + c4 * 4] = p;
        }
        __syncthreads();
        bf16x8 af[2][4];
        #pragma unroll
        for (int rt = 0; rt < 2; ++rt)
            #pragma unroll
            for (int ks = 0; ks < 4; ++ks)
                af[rt][ks] = *(const bf16x8*)&s_A[(wv * 32 + rt * 16 + nn) * SA + ks * 32 + qd * 8];
        #pragma unroll
        for (int ct = 0; ct < 8; ++ct)
            #pragma unroll
            for (int ks = 0; ks < 4; ++ks) {
                bf16x8 bf = *(const bf16x8*)&s_B[(ct * 4 + ks) * 512 + lane * 8];
                rem[0][ct] = __builtin_amdgcn_mfma_f32_16x16x32_bf16(af[0][ks], bf, rem[0][ct], 0, 0, 0);
                rem[1][ct] = __builtin_amdgcn_mfma_f32_16x16x32_bf16(af[1][ks], bf, rem[1][ct], 0, 0, 0);
            }
    }

    // latent -> s_A bf16 (wave-private rows)
    #pragma unroll
    for (int rt = 0; rt < 2; ++rt)
        #pragma unroll
        for (int ct = 0; ct < 8; ++ct)
            #pragma unroll
            for (int e = 0; e < 4; ++e)
                s_A[(wv * 32 + rt * 16 + qd * 4 + e) * SA + ct * 16 + nn] = f2bf(rem[rt][ct][e]);

    // ---- Phase 2: three RQ stages (halves rotated within each stage) ----
    float local_rq = 0.f;
    for (int t = 0; t < 3; ++t) {
        const float* __restrict__ cb = cbs[t];
        float bv[2][4]; int bi[2][4];
        #pragma unroll
        for (int rt = 0; rt < 2; ++rt)
            #pragma unroll
            for (int e = 0; e < 4; ++e) { bv[rt][e] = -3.402823466e38f; bi[rt][e] = 0; }

        bf16x8 af[2][4];
        #pragma unroll
        for (int rt = 0; rt < 2; ++rt)
            #pragma unroll
            for (int ks = 0; ks < 4; ++ks)
                af[rt][ks] = *(const bf16x8*)&s_A[(wv * 32 + rt * 16 + nn) * SA + ks * 32 + qd * 8];

        for (int hh = 0; hh < 2; ++hh) {
            const int half = hh ^ (rot & 1);
            __syncthreads();
            STAGEB(wsb + 65536 + (t * 2 + half) * 16384);
            __syncthreads();
            #pragma unroll
            for (int ct = 0; ct < 8; ++ct) {
                f32x4 s0 = {0.f,0.f,0.f,0.f}, s1 = {0.f,0.f,0.f,0.f};
                #pragma unroll
                for (int ks = 0; ks < 4; ++ks) {
                    bf16x8 bf = *(const bf16x8*)&s_B[(ct * 4 + ks) * 512 + lane * 8];
                    s0 = __builtin_amdgcn_mfma_f32_16x16x32_bf16(af[0][ks], bf, s0, 0, 0, 0);
                    s1 = __builtin_amdgcn_mfma_f32_16x16x32_bf16(af[1][ks], bf, s1, 0, 0, 0);
                }
                const int code = half * 128 + ct * 16 + nn;
                const float cn = s_cn[t * K_CODES + code];
                #pragma unroll
                for (int e = 0; e < 4; ++e) {
                    const float v0 = s0[e] + cn;
                    if (v0 > bv[0][e] || (v0 == bv[0][e] && code < bi[0][e])) { bv[0][e] = v0; bi[0][e] = code; }
                    const float v1 = s1[e] + cn;
                    if (v1 > bv[1][e] || (v1 == bv[1][e] && code < bi[1][e])) { bv[1][e] = v1; bi[1][e] = code; }
                }
            }
        }
        // argmax over the 16 nn-lanes of each quad (tie -> lowest index)
        #pragma unroll
        for (int rt = 0; rt < 2; ++rt)
            #pragma unroll
            for (int e = 0; e < 4; ++e) {
                float v = bv[rt][e]; int i0 = bi[rt][e];
                #pragma unroll
                for (int m = 8; m >= 1; m >>= 1) {
                    const float ov = __shfl_xor(v, m);
                    const int   oi = __shfl_xor(i0, m);
                    if (ov > v || (ov == v && oi < i0)) { v = ov; i0 = oi; }
                }
                bi[rt][e] = i0;
                if (nn == 0) used[t * K_CODES + i0] = 1;
            }
        // update rem/res with fp32 codebook rows
        #pragma unroll
        for (int rt = 0; rt < 2; ++rt)
            #pragma unroll
            for (int ct = 0; ct < 8; ++ct)
                #pragma unroll
                for (int e = 0; e < 4; ++e) {
                    const float c = cb[(long)bi[rt][e] * D_H + ct * 16 + nn];
                    const float r = rem[rt][ct][e] - c;
                    rem[rt][ct][e] = r;
                    res[rt][ct][e] += c;
                    local_rq += r * r;
                    if (t < 2)
                        s_A[(wv * 32 + rt * 16 + qd * 4 + e) * SA + ct * 16 + nn] = f2bf(r);
                }
    }

    // restored -> s_A bf16 (wave-private)
    #pragma unroll
    for (int rt = 0; rt < 2; ++rt)
        #pragma unroll
        for (int ct = 0; ct < 8; ++ct)
            #pragma unroll
            for (int e = 0; e < 4; ++e)
                s_A[(wv * 32 + rt * 16 + qd * 4 + e) * SA + ct * 16 + nn] = f2bf(res[rt][ct][e]);

    // ---- Phase 3: recon = restored @ Wdec^T (rotated col-chunk order), diff vs fp32 emb ----
    float local_rec = 0.f;
    {
        bf16x8 af[2][4];
        #pragma unroll
        for (int rt = 0; rt < 2; ++rt)
            #pragma unroll
            for (int ks = 0; ks < 4; ++ks)
                af[rt][ks] = *(const bf16x8*)&s_A[(wv * 32 + rt * 16 + nn) * SA + ks * 32 + qd * 8];
        for (int cc = 0; cc < 4; ++cc) {
            const int c = (cc + rot) & 3;
            __syncthreads();
            STAGEB(wsb + 163840 + c * 16384);
            __syncthreads();
            #pragma unroll
            for (int ct = 0; ct < 8; ++ct) {
                f32x4 r0 = {0.f,0.f,0.f,0.f}, r1 = {0.f,0.f,0.f,0.f};
                #pragma unroll
                for (int ks = 0; ks < 4; ++ks) {
                    bf16x8 bf = *(const bf16x8*)&s_B[(ct * 4 + ks) * 512 + lane * 8];
                    r0 = __builtin_amdgcn_mfma_f32_16x16x32_bf16(af[0][ks], bf, r0, 0, 0, 0);
                    r1 = __builtin_amdgcn_mfma_f32_16x16x32_bf16(af[1][ks], bf, r1, 0, 0, 0);
                }
                const int col = c * 128 + ct * 16 + nn;
                #pragma unroll
                for (int e = 0; e < 4; ++e) {
                    const float e0 = emb[(blkRow + wv * 32 +      qd * 4 + e) * D_IN + col];
                    const float e1 = emb[(blkRow + wv * 32 + 16 + qd * 4 + e) * D_IN + col];
                    const float d0 = r0[e] - e0;
                    const float d1 = r1[e] - e1;
                    local_rec += d0 * d0 + d1 * d1;
                }
            }
        }
    }
#undef STAGEB

    // ---- wave shuffle reduce, one atomic pair per wave ----
    float r1 = local_rq, r2 = local_rec;
    #pragma unroll
    for (int m = 32; m >= 1; m >>= 1) { r1 += __shfl_xor(r1, m); r2 += __shfl_xor(r2, m); }
    if (lane == 0) { atomicAdd(acc_rq, r1); atomicAdd(acc_recon, r2); }
}

__global__ void rqvae_finalize(const float* __restrict__ acc,
                               const int* __restrict__ used,
                               float* __restrict__ out)
{
    __shared__ int s_sum[4];
    const int tid = threadIdx.x;
    for (int t = 0; t < 3; ++t) {
        int v = (used[t * K_CODES + tid] != 0) ? 1 : 0;
        #pragma unroll
        for (int off = 32; off >= 1; off >>= 1) v += __shfl_down(v, off);
        if ((tid & 63) == 0) s_sum[tid >> 6] = v;
        __syncthreads();
        if (tid == 0) out[3 + t] = (float)(s_sum[0] + s_sum[1] + s_sum[2] + s_sum[3]);
        __syncthreads();
    }
    if (tid == 0) {
        const float rq    = 1.25f * acc[0] / ((float)N_ROWS * 128.0f);
        const float recon =         acc[1] / ((float)N_ROWS * 512.0f);
        out[0] = recon + rq;
        out[1] = recon;
        out[2] = rq;
    }
}

extern "C" void kernel_launch(void* const* d_in, const int* in_sizes, int n_in,
                              void* d_out, int out_size, void* d_ws, size_t ws_size,
                              hipStream_t stream) {
    const float* emb  = (const float*)d_in[0];
    const float* Wenc = (const float*)d_in[1];
    const float* Wdec = (const float*)d_in[2];
    const float* cb0  = (const float*)d_in[3];
    const float* cb1  = (const float*)d_in[4];
    const float* cb2  = (const float*)d_in[5];

    // workspace layout (bytes): [0] 2 f32 acc | [64] 768 int used | [3200] 768 f32 norms | [8192] 448KB bf16 frags
    float* ws_f  = (float*)d_ws;
    int*   used  = (int*)((char*)d_ws + 64);
    float* norms = (float*)((char*)d_ws + 3200);
    unsigned short* wsb = (unsigned short*)((char*)d_ws + 8192);

    hipMemsetAsync(d_ws, 0, 3200, stream);
    rqvae_prep<<<115, NT, 0, stream>>>(Wenc, Wdec, cb0, cb1, cb2, wsb, norms);
    rqvae_main<<<NBLK, NT, 0, stream>>>(emb, cb0, cb1, cb2, wsb, norms,
                                        ws_f + 0, ws_f + 1, used);
    rqvae_finalize<<<1, NT, 0, stream>>>(ws_f, used, (float*)d_out);
}